// Round 7
// baseline (540.293 us; speedup 1.0000x reference)
//
#include <hip/hip_runtime.h>
#include <hip/hip_bf16.h>

typedef __attribute__((ext_vector_type(8))) short short8v;
typedef __attribute__((ext_vector_type(8))) unsigned short ushort8v;
typedef __attribute__((ext_vector_type(4))) float f32x4;

#define N_NBR 65536
#define INIT_DIM 512
#define HID 1024
#define BM 64
#define NBLK 3072   // 3 types x 1024 M-tiles; ONE type per block (register shape!)

static __device__ __forceinline__ unsigned short f2bf(float f) {
  unsigned int u = __float_as_uint(f);
  u += 0x7fff + ((u >> 16) & 1);   // round-to-nearest-even
  return (unsigned short)(u >> 16);
}

// Relayout W (3x [1024 n][512 k] f32) into MFMA-fragment order bf16:
// for tile block (t, nb 0..63, ks 0..15), the 1KB a wave reads is contiguous:
//   out[(((t*64+nb)*16)+ks)*512 + l*8 + j] = W_t[nb*16 + (l&15)][ks*32 + (l>>4)*8 + j]
__global__ __launch_bounds__(256) void k_convw(const float* __restrict__ wa,
                                               const float* __restrict__ wb,
                                               const float* __restrict__ wc,
                                               unsigned short* __restrict__ out) {
  int g = blockIdx.x * 256 + threadIdx.x;   // 0..196607
  int l = g & 63;
  int blk = g >> 6;            // (t*64+nb)*16+ks
  int ks = blk & 15;
  int tnb = blk >> 4;
  int t = tnb >> 6;
  int nb = tnb & 63;
  const float* src = (t == 0) ? wa : (t == 1) ? wb : wc;
  int n = nb * 16 + (l & 15);
  int k0 = ks * 32 + (l >> 4) * 8;
  const f32x4* p = (const f32x4*)(src + (size_t)n * INIT_DIM + k0);
  f32x4 a = p[0], b = p[1];
  ushort8v v;
  v[0]=f2bf(a.x); v[1]=f2bf(a.y); v[2]=f2bf(a.z); v[3]=f2bf(a.w);
  v[4]=f2bf(b.x); v[5]=f2bf(b.y); v[6]=f2bf(b.z); v[7]=f2bf(b.w);
  *(ushort8v*)(out + (size_t)g * 8) = v;
}

// Main: block = (type, M-tile). R1's register shape (120 VGPR) — no t-loop,
// no sacc carried across types, epilogue folded per nc-pass. Fragment-ordered
// coalesced B, decomposed-XOR-swizzle A in LDS, nt gather, partials store
// (no atomics). All 3 W types = 3MB bf16 -> resident in every XCD L2.
// Goal: VGPR+AGPR <= 256 => 2 waves/SIMD (LDS already allows 2 blocks/CU).
__global__ __launch_bounds__(256) void k_main(
    const float* __restrict__ fa, const float* __restrict__ fb, const float* __restrict__ fc,
    const int* __restrict__ na, const int* __restrict__ nb_, const int* __restrict__ nc__,
    const float* __restrict__ b1a, const float* __restrict__ b1b, const float* __restrict__ b1c,
    const unsigned short* __restrict__ wbf,   // [3][64 nb][16 ks][512] fragment-ordered bf16
    float* __restrict__ partials) {           // [NBLK][HID]
  __shared__ __align__(16) unsigned short Asm[BM * INIT_DIM];  // 64 KB
  __shared__ int idxs[BM];

  int bx = blockIdx.x;
  int t = bx >> 10;
  int mtile = bx & 1023;
  const float* feat = (t == 0) ? fa : (t == 1) ? fb : fc;
  const int*   nbr  = (t == 0) ? na : (t == 1) ? nb_ : nc__;
  const float* bias = (t == 0) ? b1a : (t == 1) ? b1b : b1c;
  const unsigned short* Wf = wbf + (size_t)t * (HID * INIT_DIM);

  int tid = threadIdx.x;
  if (tid < BM) idxs[tid] = nbr[mtile * BM + tid];
  __syncthreads();

  int wave = tid >> 6;
  int lane = tid & 63;
  int l15 = lane & 15, lg = lane >> 4;

  // A ds_read swizzle algebra: addr = r*1024 + ((ks*64 + lg*16) ^ m), m=(r&7)<<4.
  // r&7 == l15&7 (r = mf*16+l15), so m is mf-independent. Decompose:
  //   addr = r*1024 + lo + (ks*64 ^ hi), lo = (lg*16)^(m&48), hi = m&64.
  unsigned int m_  = (unsigned)(l15 & 7) << 4;
  unsigned int lo_ = ((unsigned)(lg * 16)) ^ (m_ & 48u);
  unsigned int hi_ = m_ & 64u;
  unsigned int abase = (unsigned)l15 * 1024u + lo_;

  // Stage A: 64 rows x 512 f32 -> bf16 into LDS with XOR swizzle (nt loads).
  #pragma unroll 4
  for (int it = 0; it < 16; ++it) {
    int i = it * 256 + tid;     // chunk of 8 floats
    int r = i >> 6;
    int ck = i & 63;
    const float* rowp = feat + (size_t)idxs[r] * INIT_DIM + ck * 8;
    f32x4 a = __builtin_nontemporal_load((const f32x4*)rowp);
    f32x4 b = __builtin_nontemporal_load(((const f32x4*)rowp) + 1);
    ushort8v v;
    v[0]=f2bf(a.x); v[1]=f2bf(a.y); v[2]=f2bf(a.z); v[3]=f2bf(a.w);
    v[4]=f2bf(b.x); v[5]=f2bf(b.y); v[6]=f2bf(b.z); v[7]=f2bf(b.w);
    int byte = r * 1024 + ((ck * 16) ^ ((r & 7) << 4));
    *(ushort8v*)((char*)Asm + byte) = v;
  }
  __syncthreads();

  #pragma unroll
  for (int nc_ = 0; nc_ < 4; ++nc_) {
    // Fragment-ordered B base: n_blk = wave*16 + nc_*4 + nf; nf/ks offsets
    // are compile-time immediates off one base pointer.
    const unsigned short* pB0 = Wf + ((size_t)(wave * 16 + nc_ * 4) << 13) + lane * 8;

    f32x4 acc[4][4] = {};      // [mf][nf]
    #pragma unroll
    for (int ks = 0; ks < 16; ++ks) {
      short8v Bf[4];
      #pragma unroll
      for (int nf = 0; nf < 4; ++nf)
        Bf[nf] = *(const short8v*)(pB0 + (nf << 13) + (ks << 9));
      short8v Af[4];
      #pragma unroll
      for (int mf = 0; mf < 4; ++mf) {
        unsigned int addr = abase + (unsigned)(mf * 16384) + (((unsigned)(ks * 64)) ^ hi_);
        Af[mf] = *(const short8v*)((const char*)Asm + addr);
      }
      #pragma unroll
      for (int mf = 0; mf < 4; ++mf)
        #pragma unroll
        for (int nf = 0; nf < 4; ++nf)
          acc[mf][nf] = __builtin_amdgcn_mfma_f32_16x16x32_bf16(Af[mf], Bf[nf], acc[mf][nf], 0, 0, 0);
    }

    // Epilogue folded per pass: bias + relu + row-sum + store. No sacc.
    #pragma unroll
    for (int nf = 0; nf < 4; ++nf) {
      int n = wave * 256 + nc_ * 64 + nf * 16 + l15;
      float b = bias[n];
      float s = 0.f;
      #pragma unroll
      for (int mf = 0; mf < 4; ++mf)
        #pragma unroll
        for (int r = 0; r < 4; ++r) {
          float v = acc[mf][nf][r] + b;
          s += (v > 0.f) ? v : 0.f;
        }
      s += __shfl_xor(s, 16);
      s += __shfl_xor(s, 32);
      if (lg == 0) partials[(size_t)bx * HID + n] = s;
    }
  }
}

// Column-sum of partials [NBLK][HID] -> acc[HID]. 16 blocks x 64 cols.
__global__ __launch_bounds__(256) void k_reduce(const float* __restrict__ partials,
                                                float* __restrict__ acc) {
  __shared__ float red[4][64];
  int tid = threadIdx.x;
  int c = tid & 63, rg = tid >> 6;
  int col = blockIdx.x * 64 + c;
  float s = 0.f;
  #pragma unroll 4
  for (int r = rg; r < NBLK; r += 4)
    s += partials[(size_t)r * HID + col];
  red[rg][c] = s;
  __syncthreads();
  if (rg == 0) acc[col] = red[0][c] + red[1][c] + red[2][c] + red[3][c];
}

// pooled = acc/196608 ; feat_all = relu ; logits = feat_all @ Wc.T + bc
__global__ __launch_bounds__(256) void k_final(const float* __restrict__ acc,
                                               const float* __restrict__ Wc,
                                               const float* __restrict__ bc,
                                               float* __restrict__ out) {
  __shared__ float fall[HID];
  int tid = threadIdx.x;
  const float inv = 1.f / (3.f * (float)N_NBR);
  for (int i = tid; i < HID; i += 256) {
    float p = acc[i] * inv;
    fall[i] = (p > 0.f) ? p : 0.f;
  }
  __syncthreads();
  int o = tid >> 2, q = tid & 3;
  const f32x4* w = (const f32x4*)(Wc + (size_t)o * HID + q * 256);
  const f32x4* f = (const f32x4*)(fall + q * 256);
  float s = 0.f;
  #pragma unroll 4
  for (int k = 0; k < 64; ++k) {
    f32x4 wv = w[k], fv = f[k];
    s += wv.x * fv.x + wv.y * fv.y + wv.z * fv.z + wv.w * fv.w;
  }
  s += __shfl_xor(s, 1);
  s += __shfl_xor(s, 2);
  if (q == 0) out[o] = s + bc[o];
}

extern "C" void kernel_launch(void* const* d_in, const int* in_sizes, int n_in,
                              void* d_out, int out_size, void* d_ws, size_t ws_size,
                              hipStream_t stream) {
  // inputs: 0 feat(unused), 1 fa, 2 na, 3 W1a, 4 b1a, 5 fb, 6 nb, 7 W1b, 8 b1b,
  //         9 fc, 10 nc, 11 W1c, 12 b1c, 13 Wc, 14 bc
  const float* fa  = (const float*)d_in[1];
  const int*   na  = (const int*)d_in[2];
  const float* W1a = (const float*)d_in[3];
  const float* b1a = (const float*)d_in[4];
  const float* fb  = (const float*)d_in[5];
  const int*   nb  = (const int*)d_in[6];
  const float* W1b = (const float*)d_in[7];
  const float* b1b = (const float*)d_in[8];
  const float* fc  = (const float*)d_in[9];
  const int*   nc  = (const int*)d_in[10];
  const float* W1c = (const float*)d_in[11];
  const float* b1c = (const float*)d_in[12];
  const float* Wc  = (const float*)d_in[13];
  const float* bc  = (const float*)d_in[14];
  float* out = (float*)d_out;

  float* acc = (float*)d_ws;                                          // 1024 f32
  unsigned short* wbf = (unsigned short*)((char*)d_ws + 4096);        // 3 MB bf16 fragment-ordered
  float* partials = (float*)((char*)d_ws + 4096 + 3 * HID * INIT_DIM * sizeof(unsigned short)); // 12.6 MB

  k_convw<<<768, 256, 0, stream>>>(W1a, W1b, W1c, wbf);
  k_main<<<NBLK, 256, 0, stream>>>(fa, fb, fc, na, nb, nc, b1a, b1b, b1c, wbf, partials);
  k_reduce<<<16, 256, 0, stream>>>(partials, acc);
  k_final<<<1, 256, 0, stream>>>(acc, Wc, bc, out);
}

// Round 8
// 348.115 us; speedup vs baseline: 1.5521x; 1.5521x over previous
//
#include <hip/hip_runtime.h>
#include <hip/hip_bf16.h>

typedef __attribute__((ext_vector_type(8))) short short8v;
typedef __attribute__((ext_vector_type(8))) unsigned short ushort8v;
typedef __attribute__((ext_vector_type(4))) float f32x4;
typedef __attribute__((ext_vector_type(16))) float f32x16;

#define N_NBR 65536
#define INIT_DIM 512
#define HID 1024
#define BM 64
#define NBLK 3072   // 3 types x 1024 M-tiles; one type per block

static __device__ __forceinline__ unsigned short f2bf(float f) {
  unsigned int u = __float_as_uint(f);
  u += 0x7fff + ((u >> 16) & 1);   // round-to-nearest-even
  return (unsigned short)(u >> 16);
}

// Relayout W (3x [1024 n][512 k] f32) into 32x32x16-MFMA fragment order bf16:
// tile (t, nb 0..31, ks 0..31): the 1KB a wave reads is contiguous:
//   out[(((t*32+nb)*32)+ks)*512 + l*8 + j] = W_t[nb*32 + (l&31)][ks*16 + (l>>5)*8 + j]
__global__ __launch_bounds__(256) void k_convw(const float* __restrict__ wa,
                                               const float* __restrict__ wb,
                                               const float* __restrict__ wc,
                                               unsigned short* __restrict__ out) {
  int g = blockIdx.x * 256 + threadIdx.x;   // 0..196607
  int l = g & 63;
  int blk = g >> 6;            // t*1024 + nb*32 + ks
  int ks = blk & 31;
  int nb = (blk >> 5) & 31;
  int t = blk >> 10;
  const float* src = (t == 0) ? wa : (t == 1) ? wb : wc;
  int n = nb * 32 + (l & 31);
  int k0 = ks * 16 + (l >> 5) * 8;
  const f32x4* p = (const f32x4*)(src + (size_t)n * INIT_DIM + k0);
  f32x4 a = p[0], b = p[1];
  ushort8v v;
  v[0]=f2bf(a.x); v[1]=f2bf(a.y); v[2]=f2bf(a.z); v[3]=f2bf(a.w);
  v[4]=f2bf(b.x); v[5]=f2bf(b.y); v[6]=f2bf(b.z); v[7]=f2bf(b.w);
  *(ushort8v*)(out + (size_t)g * 8) = v;
}

// Main: 32x32x16 MFMA, mf=2 x nf=4, 2 N-passes per wave. Per wave per block:
// 128 A ds_reads (4x less than 16x16 4-pass), 512 MFMA @32x32 rate,
// acc = 128 AGPR + small VGPR live set -> goal VGPR+AGPR <= 256 (2 waves/SIMD).
// 5-bit XOR swizzle keeps 32-row column reads bank-spread.
__global__ __launch_bounds__(256) void k_main(
    const float* __restrict__ fa, const float* __restrict__ fb, const float* __restrict__ fc,
    const int* __restrict__ na, const int* __restrict__ nb_, const int* __restrict__ nc__,
    const float* __restrict__ b1a, const float* __restrict__ b1b, const float* __restrict__ b1c,
    const unsigned short* __restrict__ wbf,   // [3][32 nb][32 ks][512] fragment-ordered bf16
    float* __restrict__ partials) {           // [NBLK][HID]
  __shared__ __align__(16) unsigned short Asm[BM * INIT_DIM];  // 64 KB
  __shared__ int idxs[BM];

  int bx = blockIdx.x;
  int t = bx >> 10;
  int mtile = bx & 1023;
  const float* feat = (t == 0) ? fa : (t == 1) ? fb : fc;
  const int*   nbr  = (t == 0) ? na : (t == 1) ? nb_ : nc__;
  const float* bias = (t == 0) ? b1a : (t == 1) ? b1b : b1c;
  const unsigned short* Wf = wbf + (size_t)t * (HID * INIT_DIM);

  int tid = threadIdx.x;
  if (tid < BM) idxs[tid] = nbr[mtile * BM + tid];
  __syncthreads();

  // Stage A: 64 rows x 512 f32 -> bf16 into LDS, 5-bit XOR swizzle (nt loads).
  #pragma unroll 4
  for (int it = 0; it < 16; ++it) {
    int i = it * 256 + tid;     // chunk of 8 floats
    int r = i >> 6;
    int ck = i & 63;
    const float* rowp = feat + (size_t)idxs[r] * INIT_DIM + ck * 8;
    f32x4 a = __builtin_nontemporal_load((const f32x4*)rowp);
    f32x4 b = __builtin_nontemporal_load(((const f32x4*)rowp) + 1);
    ushort8v v;
    v[0]=f2bf(a.x); v[1]=f2bf(a.y); v[2]=f2bf(a.z); v[3]=f2bf(a.w);
    v[4]=f2bf(b.x); v[5]=f2bf(b.y); v[6]=f2bf(b.z); v[7]=f2bf(b.w);
    int byte = r * 1024 + ((ck * 16) ^ ((r & 31) << 4));
    *(ushort8v*)((char*)Asm + byte) = v;
  }
  __syncthreads();

  int wave = tid >> 6;
  int lane = tid & 63;
  int l31 = lane & 31, hi = lane >> 5;

  // A read: lane reads A[row = i*32 + l31][k = ks*16 + hi*8 ..+8].
  // byte = row*1024 + ((ks*32 + hi*16) ^ (l31<<4)). Bit-split (disjoint):
  //   bit4:  (hi<<4) ^ (swz&16)      [precomputed into abase]
  //   bits>=5: (ks<<5) ^ (swz&0x1E0) [kcol per ks]
  unsigned int swz = (unsigned)l31 << 4;
  unsigned int abase = (unsigned)l31 * 1024u + (((unsigned)hi << 4) ^ (swz & 16u));
  unsigned int swzhi = swz & 0x1E0u;

  #pragma unroll
  for (int p = 0; p < 2; ++p) {
    // B base: nb index = wave*8 + p*4 + j ; offset (nb*32 + ks)*512 + lane*8
    const unsigned short* pB0 =
        Wf + (((size_t)(wave * 8 + p * 4)) << 14) + lane * 8;

    f32x16 acc[2][4] = {};     // [mf][nf] -> 128 AGPR
    #pragma unroll 4
    for (int ks = 0; ks < 32; ++ks) {
      short8v Bf[4];
      #pragma unroll
      for (int j = 0; j < 4; ++j)
        Bf[j] = *(const short8v*)(pB0 + (j << 14) + (ks << 9));
      unsigned int kcol = (((unsigned)ks << 5) ^ swzhi);
      short8v Af[2];
      #pragma unroll
      for (int i = 0; i < 2; ++i)
        Af[i] = *(const short8v*)((const char*)Asm + (abase + (unsigned)(i * 32768) + kcol));
      #pragma unroll
      for (int i = 0; i < 2; ++i)
        #pragma unroll
        for (int j = 0; j < 4; ++j)
          acc[i][j] = __builtin_amdgcn_mfma_f32_32x32x16_bf16(Af[i], Bf[j], acc[i][j], 0, 0, 0);
    }

    // Epilogue: bias + relu + column-sum over 64 rows, store partial.
    // C layout (32x32): col = l31, row = (reg&3) + 8*(reg>>2) + 4*hi (+ 32*i).
    #pragma unroll
    for (int j = 0; j < 4; ++j) {
      int n = wave * 256 + p * 128 + j * 32 + l31;
      float b = bias[n];
      float s = 0.f;
      #pragma unroll
      for (int i = 0; i < 2; ++i)
        #pragma unroll
        for (int r = 0; r < 16; ++r) {
          float v = acc[i][j][r] + b;
          s += (v > 0.f) ? v : 0.f;
        }
      s += __shfl_xor(s, 32);
      if (hi == 0) partials[(size_t)bx * HID + n] = s;
    }
  }
}

// Column-sum of partials [NBLK][HID] -> acc[HID]. 16 blocks x 64 cols.
__global__ __launch_bounds__(256) void k_reduce(const float* __restrict__ partials,
                                                float* __restrict__ acc) {
  __shared__ float red[4][64];
  int tid = threadIdx.x;
  int c = tid & 63, rg = tid >> 6;
  int col = blockIdx.x * 64 + c;
  float s = 0.f;
  #pragma unroll 4
  for (int r = rg; r < NBLK; r += 4)
    s += partials[(size_t)r * HID + col];
  red[rg][c] = s;
  __syncthreads();
  if (rg == 0) acc[col] = red[0][c] + red[1][c] + red[2][c] + red[3][c];
}

// pooled = acc/196608 ; feat_all = relu ; logits = feat_all @ Wc.T + bc
__global__ __launch_bounds__(256) void k_final(const float* __restrict__ acc,
                                               const float* __restrict__ Wc,
                                               const float* __restrict__ bc,
                                               float* __restrict__ out) {
  __shared__ float fall[HID];
  int tid = threadIdx.x;
  const float inv = 1.f / (3.f * (float)N_NBR);
  for (int i = tid; i < HID; i += 256) {
    float p = acc[i] * inv;
    fall[i] = (p > 0.f) ? p : 0.f;
  }
  __syncthreads();
  int o = tid >> 2, q = tid & 3;
  const f32x4* w = (const f32x4*)(Wc + (size_t)o * HID + q * 256);
  const f32x4* f = (const f32x4*)(fall + q * 256);
  float s = 0.f;
  #pragma unroll 4
  for (int k = 0; k < 64; ++k) {
    f32x4 wv = w[k], fv = f[k];
    s += wv.x * fv.x + wv.y * fv.y + wv.z * fv.z + wv.w * fv.w;
  }
  s += __shfl_xor(s, 1);
  s += __shfl_xor(s, 2);
  if (q == 0) out[o] = s + bc[o];
}

extern "C" void kernel_launch(void* const* d_in, const int* in_sizes, int n_in,
                              void* d_out, int out_size, void* d_ws, size_t ws_size,
                              hipStream_t stream) {
  // inputs: 0 feat(unused), 1 fa, 2 na, 3 W1a, 4 b1a, 5 fb, 6 nb, 7 W1b, 8 b1b,
  //         9 fc, 10 nc, 11 W1c, 12 b1c, 13 Wc, 14 bc
  const float* fa  = (const float*)d_in[1];
  const int*   na  = (const int*)d_in[2];
  const float* W1a = (const float*)d_in[3];
  const float* b1a = (const float*)d_in[4];
  const float* fb  = (const float*)d_in[5];
  const int*   nb  = (const int*)d_in[6];
  const float* W1b = (const float*)d_in[7];
  const float* b1b = (const float*)d_in[8];
  const float* fc  = (const float*)d_in[9];
  const int*   nc  = (const int*)d_in[10];
  const float* W1c = (const float*)d_in[11];
  const float* b1c = (const float*)d_in[12];
  const float* Wc  = (const float*)d_in[13];
  const float* bc  = (const float*)d_in[14];
  float* out = (float*)d_out;

  float* acc = (float*)d_ws;                                          // 1024 f32
  unsigned short* wbf = (unsigned short*)((char*)d_ws + 4096);        // 3 MB bf16 fragment-ordered
  float* partials = (float*)((char*)d_ws + 4096 + 3 * HID * INIT_DIM * sizeof(unsigned short)); // 12.6 MB

  k_convw<<<768, 256, 0, stream>>>(W1a, W1b, W1c, wbf);
  k_main<<<NBLK, 256, 0, stream>>>(fa, fb, fc, na, nb, nc, b1a, b1b, b1c, wbf, partials);
  k_reduce<<<16, 256, 0, stream>>>(partials, acc);
  k_final<<<1, 256, 0, stream>>>(acc, Wc, bc, out);
}

// Round 9
// 325.142 us; speedup vs baseline: 1.6617x; 1.0707x over previous
//
#include <hip/hip_runtime.h>
#include <hip/hip_bf16.h>

typedef __attribute__((ext_vector_type(8))) short short8v;
typedef __attribute__((ext_vector_type(8))) unsigned short ushort8v;
typedef __attribute__((ext_vector_type(4))) float f32x4;
typedef __attribute__((ext_vector_type(16))) float f32x16;

#define N_NBR 65536
#define INIT_DIM 512
#define HID 1024
#define BM 64
#define NBLK 3072   // 3 types x 1024 M-tiles; one type per block

static __device__ __forceinline__ unsigned short f2bf(float f) {
  unsigned int u = __float_as_uint(f);
  u += 0x7fff + ((u >> 16) & 1);   // round-to-nearest-even
  return (unsigned short)(u >> 16);
}

// Relayout W (3x [1024 n][512 k] f32) into 32x32x16-MFMA fragment order bf16:
// tile (t, nb 0..31, ks 0..31): the 1KB a wave reads is contiguous:
//   out[(((t*32+nb)*32)+ks)*512 + l*8 + j] = W_t[nb*32 + (l&31)][ks*16 + (l>>5)*8 + j]
__global__ __launch_bounds__(256) void k_convw(const float* __restrict__ wa,
                                               const float* __restrict__ wb,
                                               const float* __restrict__ wc,
                                               unsigned short* __restrict__ out) {
  int g = blockIdx.x * 256 + threadIdx.x;   // 0..196607
  int l = g & 63;
  int blk = g >> 6;            // t*1024 + nb*32 + ks
  int ks = blk & 31;
  int nb = (blk >> 5) & 31;
  int t = blk >> 10;
  const float* src = (t == 0) ? wa : (t == 1) ? wb : wc;
  int n = nb * 32 + (l & 31);
  int k0 = ks * 16 + (l >> 5) * 8;
  const f32x4* p = (const f32x4*)(src + (size_t)n * INIT_DIM + k0);
  f32x4 a = p[0], b = p[1];
  ushort8v v;
  v[0]=f2bf(a.x); v[1]=f2bf(a.y); v[2]=f2bf(a.z); v[3]=f2bf(a.w);
  v[4]=f2bf(b.x); v[5]=f2bf(b.y); v[6]=f2bf(b.z); v[7]=f2bf(b.w);
  *(ushort8v*)(out + (size_t)g * 8) = v;
}

// Main: 32x32x16 MFMA, mf=2 x nf=2, 4 N-passes per wave.
// acc = 64 AGPR (was 128) so VGPR(+~136) + AGPR <= 256 -> 2 waves/SIMD.
// R8 proof points: 5-bit swizzle -> 0 bank conflicts; MFMA floor 82us;
// 1 wave/SIMD caps MfmaUtil at ~30%. This round buys TLP, not fewer ops.
__global__ __launch_bounds__(256) void k_main(
    const float* __restrict__ fa, const float* __restrict__ fb, const float* __restrict__ fc,
    const int* __restrict__ na, const int* __restrict__ nb_, const int* __restrict__ nc__,
    const float* __restrict__ b1a, const float* __restrict__ b1b, const float* __restrict__ b1c,
    const unsigned short* __restrict__ wbf,   // [3][32 nb][32 ks][512] fragment-ordered bf16
    float* __restrict__ partials) {           // [NBLK][HID]
  __shared__ __align__(16) unsigned short Asm[BM * INIT_DIM];  // 64 KB
  __shared__ int idxs[BM];

  int bx = blockIdx.x;
  int t = bx >> 10;
  int mtile = bx & 1023;
  const float* feat = (t == 0) ? fa : (t == 1) ? fb : fc;
  const int*   nbr  = (t == 0) ? na : (t == 1) ? nb_ : nc__;
  const float* bias = (t == 0) ? b1a : (t == 1) ? b1b : b1c;
  const unsigned short* Wf = wbf + (size_t)t * (HID * INIT_DIM);

  int tid = threadIdx.x;
  if (tid < BM) idxs[tid] = nbr[mtile * BM + tid];
  __syncthreads();

  // Stage A: 64 rows x 512 f32 -> bf16 into LDS, 5-bit XOR swizzle (nt loads).
  #pragma unroll 4
  for (int it = 0; it < 16; ++it) {
    int i = it * 256 + tid;     // chunk of 8 floats
    int r = i >> 6;
    int ck = i & 63;
    const float* rowp = feat + (size_t)idxs[r] * INIT_DIM + ck * 8;
    f32x4 a = __builtin_nontemporal_load((const f32x4*)rowp);
    f32x4 b = __builtin_nontemporal_load(((const f32x4*)rowp) + 1);
    ushort8v v;
    v[0]=f2bf(a.x); v[1]=f2bf(a.y); v[2]=f2bf(a.z); v[3]=f2bf(a.w);
    v[4]=f2bf(b.x); v[5]=f2bf(b.y); v[6]=f2bf(b.z); v[7]=f2bf(b.w);
    int byte = r * 1024 + ((ck * 16) ^ ((r & 31) << 4));
    *(ushort8v*)((char*)Asm + byte) = v;
  }
  __syncthreads();

  int wave = tid >> 6;
  int lane = tid & 63;
  int l31 = lane & 31, hi = lane >> 5;

  // A read: lane reads A[row = i*32 + l31][k = ks*16 + hi*8 ..+8].
  // byte = row*1024 + ((ks*32 + hi*16) ^ (l31<<4)). Bit-split (disjoint):
  //   bit4:  (hi<<4) ^ (swz&16)      [precomputed into abase]
  //   bits>=5: (ks<<5) ^ (swz&0x1E0) [kcol per ks]
  unsigned int swz = (unsigned)l31 << 4;
  unsigned int abase = (unsigned)l31 * 1024u + (((unsigned)hi << 4) ^ (swz & 16u));
  unsigned int swzhi = swz & 0x1E0u;

  #pragma unroll
  for (int p = 0; p < 4; ++p) {
    // B base: nb index = wave*8 + p*2 + j ; offset (nb*32 + ks)*512 + lane*8
    const unsigned short* pB0 =
        Wf + (((size_t)(wave * 8 + p * 2)) << 14) + lane * 8;

    f32x16 acc[2][2] = {};     // [mf][nf] -> 64 AGPR
    #pragma unroll 4
    for (int ks = 0; ks < 32; ++ks) {
      short8v Bf[2];
      #pragma unroll
      for (int j = 0; j < 2; ++j)
        Bf[j] = *(const short8v*)(pB0 + (j << 14) + (ks << 9));
      unsigned int kcol = (((unsigned)ks << 5) ^ swzhi);
      short8v Af[2];
      #pragma unroll
      for (int i = 0; i < 2; ++i)
        Af[i] = *(const short8v*)((const char*)Asm + (abase + (unsigned)(i * 32768) + kcol));
      #pragma unroll
      for (int i = 0; i < 2; ++i)
        #pragma unroll
        for (int j = 0; j < 2; ++j)
          acc[i][j] = __builtin_amdgcn_mfma_f32_32x32x16_bf16(Af[i], Bf[j], acc[i][j], 0, 0, 0);
    }

    // Epilogue: bias + relu + column-sum over 64 rows, store partial.
    // C layout (32x32): col = l31, row = (reg&3) + 8*(reg>>2) + 4*hi (+ 32*i).
    #pragma unroll
    for (int j = 0; j < 2; ++j) {
      int n = wave * 256 + p * 64 + j * 32 + l31;
      float b = bias[n];
      float s = 0.f;
      #pragma unroll
      for (int i = 0; i < 2; ++i)
        #pragma unroll
        for (int r = 0; r < 16; ++r) {
          float v = acc[i][j][r] + b;
          s += (v > 0.f) ? v : 0.f;
        }
      s += __shfl_xor(s, 32);
      if (hi == 0) partials[(size_t)bx * HID + n] = s;
    }
  }
}

// Column-sum of partials [NBLK][HID] -> acc[HID]. 16 blocks x 64 cols.
__global__ __launch_bounds__(256) void k_reduce(const float* __restrict__ partials,
                                                float* __restrict__ acc) {
  __shared__ float red[4][64];
  int tid = threadIdx.x;
  int c = tid & 63, rg = tid >> 6;
  int col = blockIdx.x * 64 + c;
  float s = 0.f;
  #pragma unroll 4
  for (int r = rg; r < NBLK; r += 4)
    s += partials[(size_t)r * HID + col];
  red[rg][c] = s;
  __syncthreads();
  if (rg == 0) acc[col] = red[0][c] + red[1][c] + red[2][c] + red[3][c];
}

// pooled = acc/196608 ; feat_all = relu ; logits = feat_all @ Wc.T + bc
__global__ __launch_bounds__(256) void k_final(const float* __restrict__ acc,
                                               const float* __restrict__ Wc,
                                               const float* __restrict__ bc,
                                               float* __restrict__ out) {
  __shared__ float fall[HID];
  int tid = threadIdx.x;
  const float inv = 1.f / (3.f * (float)N_NBR);
  for (int i = tid; i < HID; i += 256) {
    float p = acc[i] * inv;
    fall[i] = (p > 0.f) ? p : 0.f;
  }
  __syncthreads();
  int o = tid >> 2, q = tid & 3;
  const f32x4* w = (const f32x4*)(Wc + (size_t)o * HID + q * 256);
  const f32x4* f = (const f32x4*)(fall + q * 256);
  float s = 0.f;
  #pragma unroll 4
  for (int k = 0; k < 64; ++k) {
    f32x4 wv = w[k], fv = f[k];
    s += wv.x * fv.x + wv.y * fv.y + wv.z * fv.z + wv.w * fv.w;
  }
  s += __shfl_xor(s, 1);
  s += __shfl_xor(s, 2);
  if (q == 0) out[o] = s + bc[o];
}

extern "C" void kernel_launch(void* const* d_in, const int* in_sizes, int n_in,
                              void* d_out, int out_size, void* d_ws, size_t ws_size,
                              hipStream_t stream) {
  // inputs: 0 feat(unused), 1 fa, 2 na, 3 W1a, 4 b1a, 5 fb, 6 nb, 7 W1b, 8 b1b,
  //         9 fc, 10 nc, 11 W1c, 12 b1c, 13 Wc, 14 bc
  const float* fa  = (const float*)d_in[1];
  const int*   na  = (const int*)d_in[2];
  const float* W1a = (const float*)d_in[3];
  const float* b1a = (const float*)d_in[4];
  const float* fb  = (const float*)d_in[5];
  const int*   nb  = (const int*)d_in[6];
  const float* W1b = (const float*)d_in[7];
  const float* b1b = (const float*)d_in[8];
  const float* fc  = (const float*)d_in[9];
  const int*   nc  = (const int*)d_in[10];
  const float* W1c = (const float*)d_in[11];
  const float* b1c = (const float*)d_in[12];
  const float* Wc  = (const float*)d_in[13];
  const float* bc  = (const float*)d_in[14];
  float* out = (float*)d_out;

  float* acc = (float*)d_ws;                                          // 1024 f32
  unsigned short* wbf = (unsigned short*)((char*)d_ws + 4096);        // 3 MB bf16 fragment-ordered
  float* partials = (float*)((char*)d_ws + 4096 + 3 * HID * INIT_DIM * sizeof(unsigned short)); // 12.6 MB

  k_convw<<<768, 256, 0, stream>>>(W1a, W1b, W1c, wbf);
  k_main<<<NBLK, 256, 0, stream>>>(fa, fb, fc, na, nb, nc, b1a, b1b, b1c, wbf, partials);
  k_reduce<<<16, 256, 0, stream>>>(partials, acc);
  k_final<<<1, 256, 0, stream>>>(acc, Wc, bc, out);
}